// Round 1
// baseline (19658.661 us; speedup 1.0000x reference)
//
#include <hip/hip_runtime.h>
#include <hip/hip_cooperative_groups.h>
#include <math.h>

namespace cg = cooperative_groups;

#define TSTEPS 512
#define BATCH  16
#define DIMSZ  1024
#define NBANK  4
#define ZD     5120            // (1+NB)*DIM
#define HN     16384           // BATCH*DIMSZ
#define MROWS  8192            // TSTEPS*BATCH

// workspace layout (float offsets)
#define WS_WHS  0u
#define WS_PRE  1048576u
#define WS_HSEQ 9437184u
#define WS_U    17825792u
#define WS_V    17826816u
#define WS_TMP  17827840u
#define WS_SC   17828864u

// ---------------- spectral norm helpers ----------------

// normalize a 1024-vector; optionally write the Wh scale factor
__global__ __launch_bounds__(256) void k_normvec(const float* __restrict__ in,
                                                 float* __restrict__ outv,
                                                 float* __restrict__ sc,
                                                 int use_eps, int write_scale) {
    __shared__ float red[256];
    int tid = threadIdx.x;
    float4 v = *(const float4*)(in + tid * 4);
    red[tid] = v.x*v.x + v.y*v.y + v.z*v.z + v.w*v.w;
    __syncthreads();
    for (int off = 128; off > 0; off >>= 1) {
        if (tid < off) red[tid] += red[tid + off];
        __syncthreads();
    }
    float total = red[0];
    float nrm   = sqrtf(total);
    float denom = use_eps ? (nrm + 1e-8f) : nrm;
    float inv   = 1.0f / denom;
    float4 o;
    o.x = v.x * inv; o.y = v.y * inv; o.z = v.z * inv; o.w = v.w * inv;
    *(float4*)(outv + tid * 4) = o;
    if (write_scale && tid == 0) {
        // sigma = |u . (W_h v)| = ||tmp||^2 / (||tmp|| + 1e-8)
        float sigma = total / denom;
        sc[0] = 0.99f / (sigma + 1e-8f);
    }
}

// tmp = W_h^T @ u   (block computes 4 outputs i0..i0+3)
__global__ __launch_bounds__(256) void k_matvecT(const float* __restrict__ W,
                                                 const float* __restrict__ vin,
                                                 float* __restrict__ vout) {
    __shared__ float4 red[256];
    int tid = threadIdx.x;
    int i0  = blockIdx.x * 4;
    float4 acc = make_float4(0.f, 0.f, 0.f, 0.f);
#pragma unroll
    for (int q = 0; q < 4; ++q) {
        int j = tid * 4 + q;
        float u = vin[j];
        float4 w = *(const float4*)(W + (size_t)j * DIMSZ + i0);
        acc.x += u * w.x; acc.y += u * w.y; acc.z += u * w.z; acc.w += u * w.w;
    }
    red[tid] = acc;
    __syncthreads();
    for (int off = 128; off > 0; off >>= 1) {
        if (tid < off) {
            float4 a = red[tid], b = red[tid + off];
            a.x += b.x; a.y += b.y; a.z += b.z; a.w += b.w;
            red[tid] = a;
        }
        __syncthreads();
    }
    if (tid == 0) *(float4*)(vout + i0) = red[0];
}

// tmp = W_h @ v   (block computes rows i0..i0+3)
__global__ __launch_bounds__(256) void k_matvecN(const float* __restrict__ W,
                                                 const float* __restrict__ vin,
                                                 float* __restrict__ vout) {
    __shared__ float red[256];
    int tid = threadIdx.x;
    int i0  = blockIdx.x * 4;
    int ii  = tid >> 6, jg = tid & 63;
    const float* wr = W + (size_t)(i0 + ii) * DIMSZ + jg * 16;
    const float* vv = vin + jg * 16;
    float s = 0.f;
#pragma unroll
    for (int q = 0; q < 4; ++q) {
        float4 w = *(const float4*)(wr + q * 4);
        float4 v = *(const float4*)(vv + q * 4);
        s += w.x*v.x + w.y*v.y + w.z*v.z + w.w*v.w;
    }
    red[tid] = s;
    __syncthreads();
    if (tid < 4) {
        float t2 = 0.f;
        for (int j = 0; j < 64; ++j) t2 += red[tid * 64 + j];
        vout[i0 + tid] = t2;
    }
}

// Wh_scaled = W_h * scale
__global__ __launch_bounds__(256) void k_scalewh(const float* __restrict__ W,
                                                 float* __restrict__ Ws,
                                                 const float* __restrict__ sc) {
    float s = sc[0];
    size_t idx = ((size_t)blockIdx.x * 256 + threadIdx.x) * 4;
    float4 v = *(const float4*)(W + idx);
    v.x *= s; v.y *= s; v.z *= s; v.w *= s;
    *(float4*)(Ws + idx) = v;
}

// ---------------- pre_x = x @ W_x^T + b ----------------
// M=8192, N=1024, K=1024; both operands row-major with K contiguous (NT gemm).
__global__ __launch_bounds__(256) void k_pregemm(const float* __restrict__ A,
                                                 const float* __restrict__ W,
                                                 const float* __restrict__ bias,
                                                 float* __restrict__ outp) {
    __shared__ __align__(16) float As[16][68];
    __shared__ __align__(16) float Bs[16][68];
    int tid = threadIdx.x;
    int bn = blockIdx.x * 64;
    int bm = blockIdx.y * 64;
    int tx = tid & 15, ty = tid >> 4;
    int lrow = tid >> 2;
    int lk   = (tid & 3) * 4;
    const float* Ap = A + (size_t)(bm + lrow) * DIMSZ + lk;
    const float* Wp = W + (size_t)(bn + lrow) * DIMSZ + lk;
    float acc[4][4] = {{0.f}};
    for (int k0 = 0; k0 < DIMSZ; k0 += 16) {
        float4 av = *(const float4*)(Ap + k0);
        float4 wv = *(const float4*)(Wp + k0);
        __syncthreads();
        As[lk+0][lrow] = av.x; As[lk+1][lrow] = av.y; As[lk+2][lrow] = av.z; As[lk+3][lrow] = av.w;
        Bs[lk+0][lrow] = wv.x; Bs[lk+1][lrow] = wv.y; Bs[lk+2][lrow] = wv.z; Bs[lk+3][lrow] = wv.w;
        __syncthreads();
#pragma unroll
        for (int kk = 0; kk < 16; ++kk) {
            float4 a4 = *(const float4*)&As[kk][ty * 4];
            float4 b4 = *(const float4*)&Bs[kk][tx * 4];
            acc[0][0] += a4.x*b4.x; acc[0][1] += a4.x*b4.y; acc[0][2] += a4.x*b4.z; acc[0][3] += a4.x*b4.w;
            acc[1][0] += a4.y*b4.x; acc[1][1] += a4.y*b4.y; acc[1][2] += a4.y*b4.z; acc[1][3] += a4.y*b4.w;
            acc[2][0] += a4.z*b4.x; acc[2][1] += a4.z*b4.y; acc[2][2] += a4.z*b4.z; acc[2][3] += a4.z*b4.w;
            acc[3][0] += a4.w*b4.x; acc[3][1] += a4.w*b4.y; acc[3][2] += a4.w*b4.z; acc[3][3] += a4.w*b4.w;
        }
    }
    float4 bb = *(const float4*)(bias + bn + tx * 4);
#pragma unroll
    for (int i = 0; i < 4; ++i) {
        float4 o;
        o.x = acc[i][0] + bb.x; o.y = acc[i][1] + bb.y;
        o.z = acc[i][2] + bb.z; o.w = acc[i][3] + bb.w;
        *(float4*)(outp + (size_t)(bm + ty * 4 + i) * DIMSZ + bn + tx * 4) = o;
    }
}

// ---------------- sequential h-scan (cooperative) ----------------
// 256 blocks x 256 threads; block owns 4 output columns j0..j0+3 for all batches.
// Wh rows staged once into LDS; one grid.sync per timestep.
__global__ __launch_bounds__(256) void k_scan(const float* __restrict__ h0,
                                              const float* __restrict__ pre,
                                              const float* __restrict__ whs,
                                              float* __restrict__ hseq) {
    cg::grid_group grid = cg::this_grid();
    __shared__ __align__(16) float wsh[4 * DIMSZ];
    __shared__ float sred[256];
    int tid = threadIdx.x, bid = blockIdx.x;
    int j0 = bid * 4;
#pragma unroll
    for (int r = 0; r < 4; ++r)
        *(float4*)&wsh[r * DIMSZ + tid * 4] =
            *(const float4*)(whs + (size_t)(j0 + r) * DIMSZ + tid * 4);
    __syncthreads();
    int b = tid >> 4, jj = (tid >> 2) & 3, dg = tid & 3;
    const float* wrow = &wsh[jj * DIMSZ + dg * 256];
    for (int t = 0; t < TSTEPS; ++t) {
        const float* hp = (t == 0) ? h0 : (hseq + (size_t)(t - 1) * HN);
        const float* hv = hp + b * DIMSZ + dg * 256;
        float acc = 0.f;
#pragma unroll 8
        for (int i = 0; i < 256; i += 4) {
            float4 h4 = *(const float4*)(hv + i);
            float4 w4 = *(const float4*)(wrow + i);
            acc += h4.x*w4.x + h4.y*w4.y + h4.z*w4.z + h4.w*w4.w;
        }
        sred[tid] = acc;
        __syncthreads();
        if (dg == 0) {
            float s = sred[tid] + sred[tid + 1] + sred[tid + 2] + sred[tid + 3];
            s += pre[(size_t)t * HN + b * DIMSZ + j0 + jj];
            hseq[(size_t)t * HN + b * DIMSZ + j0 + jj] = tanhf(s);
        }
        grid.sync();
    }
}

// ---------------- m-banks + output ----------------
// one thread per (b,d); m[k] carried in registers across t.
__global__ __launch_bounds__(128) void k_out(const float* __restrict__ hseq,
                                             const float* __restrict__ z,
                                             const float* __restrict__ m0,
                                             const float* __restrict__ a,
                                             float* __restrict__ out) {
    int gt = blockIdx.x * 128 + threadIdx.x;   // 0..16383
    int b = gt >> 10, d = gt & 1023;
    float al[NBANK], om[NBANK], m[NBANK];
#pragma unroll
    for (int k = 0; k < NBANK; ++k) {
        float av = a[k * DIMSZ + d];
        al[k] = 1.0f / (1.0f + expf(-av));
        om[k] = 1.0f - al[k];
        m[k]  = m0[(size_t)k * HN + b * DIMSZ + d];
    }
    const float* zb = z + (size_t)b * ZD + d;
    const float* hb = hseq + (size_t)b * DIMSZ + d;
    float* ob = out + (size_t)b * DIMSZ + d;
    float h = 0.f;
    for (int t = 0; t < TSTEPS; ++t) {
        h = hb[(size_t)t * HN];
        const float* zt = zb + (size_t)t * (BATCH * ZD);
        float z0 = zt[0];
        float o = h * (z0 / (1.0f + expf(-z0)));
#pragma unroll
        for (int k = 0; k < NBANK; ++k) {
            m[k] = al[k] * m[k] + om[k] * h;
            float zk = zt[(k + 1) * DIMSZ];
            o += m[k] * (zk / (1.0f + expf(-zk)));
        }
        ob[(size_t)t * HN] = o;
    }
    out[(size_t)TSTEPS * HN + b * DIMSZ + d] = h;
#pragma unroll
    for (int k = 0; k < NBANK; ++k)
        out[(size_t)TSTEPS * HN + HN + (size_t)k * HN + b * DIMSZ + d] = m[k];
}

// ---------------- launch ----------------
extern "C" void kernel_launch(void* const* d_in, const int* in_sizes, int n_in,
                              void* d_out, int out_size, void* d_ws, size_t ws_size,
                              hipStream_t stream) {
    const float* x    = (const float*)d_in[0];
    const float* z    = (const float*)d_in[1];
    const float* h0   = (const float*)d_in[2];
    const float* m0   = (const float*)d_in[3];
    const float* Wx   = (const float*)d_in[4];
    const float* Wh   = (const float*)d_in[5];
    const float* bias = (const float*)d_in[6];
    const float* a    = (const float*)d_in[7];
    const float* u0   = (const float*)d_in[8];
    float* out = (float*)d_out;
    float* ws  = (float*)d_ws;

    float* WHS  = ws + WS_WHS;
    float* PRE  = ws + WS_PRE;
    float* HSEQ = ws + WS_HSEQ;
    float* U    = ws + WS_U;
    float* V    = ws + WS_V;
    float* TMP  = ws + WS_TMP;
    float* SC   = ws + WS_SC;

    // spectral normalization of W_h
    k_normvec<<<1, 256, 0, stream>>>(u0, U, SC, 0, 0);
    for (int it = 0; it < 3; ++it) {
        k_matvecT<<<256, 256, 0, stream>>>(Wh, U, TMP);
        k_normvec<<<1, 256, 0, stream>>>(TMP, V, SC, 1, 0);
        k_matvecN<<<256, 256, 0, stream>>>(Wh, V, TMP);
        k_normvec<<<1, 256, 0, stream>>>(TMP, U, SC, 1, (it == 2) ? 1 : 0);
    }
    k_scalewh<<<1024, 256, 0, stream>>>(Wh, WHS, SC);

    // pre_x = x @ W_x^T + b
    dim3 gg(16, 128);
    k_pregemm<<<gg, 256, 0, stream>>>(x, Wx, bias, PRE);

    // sequential scan over T (cooperative, grid.sync per step)
    {
        const float* h0p = h0;
        const float* prep = PRE;
        const float* whsp = WHS;
        float* hseqp = HSEQ;
        void* args[4] = {(void*)&h0p, (void*)&prep, (void*)&whsp, (void*)&hseqp};
        hipLaunchCooperativeKernel(reinterpret_cast<const void*>(&k_scan),
                                   dim3(256), dim3(256), args, 0, stream);
    }

    // m banks + output
    k_out<<<128, 128, 0, stream>>>(HSEQ, z, m0, a, out);
}

// Round 2
// 19562.651 us; speedup vs baseline: 1.0049x; 1.0049x over previous
//
#include <hip/hip_runtime.h>
#include <math.h>

#define TSTEPS 512
#define BATCH  16
#define DIMSZ  1024
#define NBANK  4
#define ZD     5120            // (1+NB)*DIM
#define HN     16384           // BATCH*DIMSZ

// scan decomposition
#define GROUPS    8
#define BLK_PER_G 32
#define ROWS_PB   32
#define S_WH      1032         // padded LDS stride (floats): bank-conflict-free

// workspace layout (float offsets)
#define WS_WHS  0u
#define WS_PRE  1048576u
#define WS_HSEQ 9437184u
#define WS_U    17825792u
#define WS_V    17826816u
#define WS_TMP  17827840u
#define WS_SC   17828864u
#define WS_BAR  17829120u      // 8 groups x 64 uints (cnt at +0, epoch at +16)

// ---------------- spectral norm helpers ----------------

__global__ __launch_bounds__(256) void k_normvec(const float* __restrict__ in,
                                                 float* __restrict__ outv,
                                                 float* __restrict__ sc,
                                                 int use_eps, int write_scale) {
    __shared__ float red[256];
    int tid = threadIdx.x;
    float4 v = *(const float4*)(in + tid * 4);
    red[tid] = v.x*v.x + v.y*v.y + v.z*v.z + v.w*v.w;
    __syncthreads();
    for (int off = 128; off > 0; off >>= 1) {
        if (tid < off) red[tid] += red[tid + off];
        __syncthreads();
    }
    float total = red[0];
    float nrm   = sqrtf(total);
    float denom = use_eps ? (nrm + 1e-8f) : nrm;
    float inv   = 1.0f / denom;
    float4 o;
    o.x = v.x * inv; o.y = v.y * inv; o.z = v.z * inv; o.w = v.w * inv;
    *(float4*)(outv + tid * 4) = o;
    if (write_scale && tid == 0) {
        float sigma = total / denom;
        sc[0] = 0.99f / (sigma + 1e-8f);
    }
}

__global__ __launch_bounds__(256) void k_matvecT(const float* __restrict__ W,
                                                 const float* __restrict__ vin,
                                                 float* __restrict__ vout) {
    __shared__ float4 red[256];
    int tid = threadIdx.x;
    int i0  = blockIdx.x * 4;
    float4 acc = make_float4(0.f, 0.f, 0.f, 0.f);
#pragma unroll
    for (int q = 0; q < 4; ++q) {
        int j = tid * 4 + q;
        float u = vin[j];
        float4 w = *(const float4*)(W + (size_t)j * DIMSZ + i0);
        acc.x += u * w.x; acc.y += u * w.y; acc.z += u * w.z; acc.w += u * w.w;
    }
    red[tid] = acc;
    __syncthreads();
    for (int off = 128; off > 0; off >>= 1) {
        if (tid < off) {
            float4 a = red[tid], b = red[tid + off];
            a.x += b.x; a.y += b.y; a.z += b.z; a.w += b.w;
            red[tid] = a;
        }
        __syncthreads();
    }
    if (tid == 0) *(float4*)(vout + i0) = red[0];
}

__global__ __launch_bounds__(256) void k_matvecN(const float* __restrict__ W,
                                                 const float* __restrict__ vin,
                                                 float* __restrict__ vout) {
    __shared__ float red[256];
    int tid = threadIdx.x;
    int i0  = blockIdx.x * 4;
    int ii  = tid >> 6, jg = tid & 63;
    const float* wr = W + (size_t)(i0 + ii) * DIMSZ + jg * 16;
    const float* vv = vin + jg * 16;
    float s = 0.f;
#pragma unroll
    for (int q = 0; q < 4; ++q) {
        float4 w = *(const float4*)(wr + q * 4);
        float4 v = *(const float4*)(vv + q * 4);
        s += w.x*v.x + w.y*v.y + w.z*v.z + w.w*v.w;
    }
    red[tid] = s;
    __syncthreads();
    if (tid < 4) {
        float t2 = 0.f;
        for (int j = 0; j < 64; ++j) t2 += red[tid * 64 + j];
        vout[i0 + tid] = t2;
    }
}

__global__ __launch_bounds__(256) void k_scalewh(const float* __restrict__ W,
                                                 float* __restrict__ Ws,
                                                 const float* __restrict__ sc) {
    float s = sc[0];
    size_t idx = ((size_t)blockIdx.x * 256 + threadIdx.x) * 4;
    float4 v = *(const float4*)(W + idx);
    v.x *= s; v.y *= s; v.z *= s; v.w *= s;
    *(float4*)(Ws + idx) = v;
}

// zero the barrier flags (ws is poisoned 0xAA before every launch)
__global__ __launch_bounds__(256) void k_zero(unsigned* __restrict__ p) {
    p[blockIdx.x * 256 + threadIdx.x] = 0u;
}

// ---------------- pre_x = x @ W_x^T + b ----------------
__global__ __launch_bounds__(256) void k_pregemm(const float* __restrict__ A,
                                                 const float* __restrict__ W,
                                                 const float* __restrict__ bias,
                                                 float* __restrict__ outp) {
    __shared__ __align__(16) float As[16][68];
    __shared__ __align__(16) float Bs[16][68];
    int tid = threadIdx.x;
    int bn = blockIdx.x * 64;
    int bm = blockIdx.y * 64;
    int tx = tid & 15, ty = tid >> 4;
    int lrow = tid >> 2;
    int lk   = (tid & 3) * 4;
    const float* Ap = A + (size_t)(bm + lrow) * DIMSZ + lk;
    const float* Wp = W + (size_t)(bn + lrow) * DIMSZ + lk;
    float acc[4][4] = {{0.f}};
    for (int k0 = 0; k0 < DIMSZ; k0 += 16) {
        float4 av = *(const float4*)(Ap + k0);
        float4 wv = *(const float4*)(Wp + k0);
        __syncthreads();
        As[lk+0][lrow] = av.x; As[lk+1][lrow] = av.y; As[lk+2][lrow] = av.z; As[lk+3][lrow] = av.w;
        Bs[lk+0][lrow] = wv.x; Bs[lk+1][lrow] = wv.y; Bs[lk+2][lrow] = wv.z; Bs[lk+3][lrow] = wv.w;
        __syncthreads();
#pragma unroll
        for (int kk = 0; kk < 16; ++kk) {
            float4 a4 = *(const float4*)&As[kk][ty * 4];
            float4 b4 = *(const float4*)&Bs[kk][tx * 4];
            acc[0][0] += a4.x*b4.x; acc[0][1] += a4.x*b4.y; acc[0][2] += a4.x*b4.z; acc[0][3] += a4.x*b4.w;
            acc[1][0] += a4.y*b4.x; acc[1][1] += a4.y*b4.y; acc[1][2] += a4.y*b4.z; acc[1][3] += a4.y*b4.w;
            acc[2][0] += a4.z*b4.x; acc[2][1] += a4.z*b4.y; acc[2][2] += a4.z*b4.z; acc[2][3] += a4.z*b4.w;
            acc[3][0] += a4.w*b4.x; acc[3][1] += a4.w*b4.y; acc[3][2] += a4.w*b4.z; acc[3][3] += a4.w*b4.w;
        }
    }
    float4 bb = *(const float4*)(bias + bn + tx * 4);
#pragma unroll
    for (int i = 0; i < 4; ++i) {
        float4 o;
        o.x = acc[i][0] + bb.x; o.y = acc[i][1] + bb.y;
        o.z = acc[i][2] + bb.z; o.w = acc[i][3] + bb.w;
        *(float4*)(outp + (size_t)(bm + ty * 4 + i) * DIMSZ + bn + tx * 4) = o;
    }
}

// ---------------- sequential h-scan: per-group barrier version ----------------
// 256 blocks: group g = bid>>5 owns batches {2g, 2g+1}; block s = bid&31 owns
// rows [32s, 32s+32). Wh slice lives in LDS for the whole kernel. One 32-block
// epoch barrier per step (groups independent -> no grid-wide convoy).

__device__ inline void group_barrier(unsigned* cnt, unsigned* epoch, unsigned target) {
    __syncthreads();
    if (threadIdx.x == 0) {
        __threadfence();   // release: make this block's h stores visible (device scope)
        unsigned old = __hip_atomic_fetch_add(cnt, 1u, __ATOMIC_ACQ_REL, __HIP_MEMORY_SCOPE_AGENT);
        if (old == BLK_PER_G - 1) {
            __hip_atomic_store(cnt, 0u, __ATOMIC_RELAXED, __HIP_MEMORY_SCOPE_AGENT);
            __hip_atomic_fetch_add(epoch, 1u, __ATOMIC_RELEASE, __HIP_MEMORY_SCOPE_AGENT);
        } else {
            while (__hip_atomic_load(epoch, __ATOMIC_ACQUIRE, __HIP_MEMORY_SCOPE_AGENT) < target) {}
        }
    }
    __syncthreads();
    __threadfence();       // acquire: invalidate L1 so next step's loads see L2
}

extern __shared__ float smem[];

__global__ void k_scan_fused(const float* __restrict__ h0,
                             const float* __restrict__ pre,
                             const float* __restrict__ whs,
                             float* __restrict__ hseq,
                             unsigned* __restrict__ bar) {
    float* wsh = smem;                       // [ROWS_PB][S_WH]
    float* hs  = smem + ROWS_PB * S_WH;      // [2][DIMSZ]
    int tid = threadIdx.x, bid = blockIdx.x;
    int g = bid >> 5, s = bid & 31;
    int b0 = g * 2;
    int j0 = s * ROWS_PB;
    unsigned* cnt   = (unsigned*)bar + (size_t)g * 64;
    unsigned* epoch = (unsigned*)bar + (size_t)g * 64 + 16;

    // stage Wh rows once (padded stride -> conflict-free ds_read_b128 later)
    for (int r = 0; r < ROWS_PB; ++r)
        *(float4*)&wsh[r * S_WH + tid * 4] =
            *(const float4*)(whs + (size_t)(j0 + r) * DIMSZ + tid * 4);
    __syncthreads();

    int rg = tid >> 5;   // 0..7 -> rows rg*4..rg*4+3
    int dg = tid & 31;   // k-split lane

    for (int t = 0; t < TSTEPS; ++t) {
        // stage h_old (both batches) into LDS with L1-bypassing loads
        const float* hp = (t == 0) ? h0 : (hseq + (size_t)(t - 1) * HN);
#pragma unroll
        for (int q = 0; q < 8; ++q) {
            int idx = q * 256 + tid;         // 0..2047
            int bb = idx >> 10, k = idx & 1023;
            hs[idx] = __hip_atomic_load(hp + (size_t)(b0 + bb) * DIMSZ + k,
                                        __ATOMIC_RELAXED, __HIP_MEMORY_SCOPE_AGENT);
        }
        __syncthreads();

        float acc[4][2] = {{0.f, 0.f}, {0.f, 0.f}, {0.f, 0.f}, {0.f, 0.f}};
#pragma unroll
        for (int i = 0; i < 8; ++i) {
            int k = dg * 4 + i * 128;
            float4 ha = *(float4*)&hs[k];
            float4 hb = *(float4*)&hs[1024 + k];
#pragma unroll
            for (int rr = 0; rr < 4; ++rr) {
                float4 w = *(float4*)&wsh[(rg * 4 + rr) * S_WH + k];
                acc[rr][0] += w.x*ha.x + w.y*ha.y + w.z*ha.z + w.w*ha.w;
                acc[rr][1] += w.x*hb.x + w.y*hb.y + w.z*hb.z + w.w*hb.w;
            }
        }
        // reduce across the 32 k-split lanes (half-wave)
#pragma unroll
        for (int off = 16; off > 0; off >>= 1)
#pragma unroll
            for (int rr = 0; rr < 4; ++rr) {
                acc[rr][0] += __shfl_down(acc[rr][0], off, 32);
                acc[rr][1] += __shfl_down(acc[rr][1], off, 32);
            }
        if (dg == 0) {
            const float* prow = pre + (size_t)t * HN;
            float* hrow = hseq + (size_t)t * HN;
#pragma unroll
            for (int bb = 0; bb < 2; ++bb) {
                float4 p4 = *(const float4*)(prow + (size_t)(b0 + bb) * DIMSZ + j0 + rg * 4);
                float4 o;
                o.x = tanhf(acc[0][bb] + p4.x);
                o.y = tanhf(acc[1][bb] + p4.y);
                o.z = tanhf(acc[2][bb] + p4.z);
                o.w = tanhf(acc[3][bb] + p4.w);
                *(float4*)(hrow + (size_t)(b0 + bb) * DIMSZ + j0 + rg * 4) = o;
            }
        }
        group_barrier(cnt, epoch, (unsigned)(t + 1));
    }
}

// ---------------- m-banks + output ----------------
__global__ __launch_bounds__(128) void k_out(const float* __restrict__ hseq,
                                             const float* __restrict__ z,
                                             const float* __restrict__ m0,
                                             const float* __restrict__ a,
                                             float* __restrict__ out) {
    int gt = blockIdx.x * 128 + threadIdx.x;   // 0..16383
    int b = gt >> 10, d = gt & 1023;
    float al[NBANK], om[NBANK], m[NBANK];
#pragma unroll
    for (int k = 0; k < NBANK; ++k) {
        float av = a[k * DIMSZ + d];
        al[k] = 1.0f / (1.0f + expf(-av));
        om[k] = 1.0f - al[k];
        m[k]  = m0[(size_t)k * HN + b * DIMSZ + d];
    }
    const float* zb = z + (size_t)b * ZD + d;
    const float* hb = hseq + (size_t)b * DIMSZ + d;
    float* ob = out + (size_t)b * DIMSZ + d;
    float h = 0.f;
    for (int t = 0; t < TSTEPS; ++t) {
        h = hb[(size_t)t * HN];
        const float* zt = zb + (size_t)t * (BATCH * ZD);
        float z0 = zt[0];
        float o = h * (z0 / (1.0f + expf(-z0)));
#pragma unroll
        for (int k = 0; k < NBANK; ++k) {
            m[k] = al[k] * m[k] + om[k] * h;
            float zk = zt[(k + 1) * DIMSZ];
            o += m[k] * (zk / (1.0f + expf(-zk)));
        }
        ob[(size_t)t * HN] = o;
    }
    out[(size_t)TSTEPS * HN + b * DIMSZ + d] = h;
#pragma unroll
    for (int k = 0; k < NBANK; ++k)
        out[(size_t)TSTEPS * HN + HN + (size_t)k * HN + b * DIMSZ + d] = m[k];
}

// ---------------- launch ----------------
extern "C" void kernel_launch(void* const* d_in, const int* in_sizes, int n_in,
                              void* d_out, int out_size, void* d_ws, size_t ws_size,
                              hipStream_t stream) {
    const float* x    = (const float*)d_in[0];
    const float* z    = (const float*)d_in[1];
    const float* h0   = (const float*)d_in[2];
    const float* m0   = (const float*)d_in[3];
    const float* Wx   = (const float*)d_in[4];
    const float* Wh   = (const float*)d_in[5];
    const float* bias = (const float*)d_in[6];
    const float* a    = (const float*)d_in[7];
    const float* u0   = (const float*)d_in[8];
    float* out = (float*)d_out;
    float* ws  = (float*)d_ws;

    float* WHS  = ws + WS_WHS;
    float* PRE  = ws + WS_PRE;
    float* HSEQ = ws + WS_HSEQ;
    float* U    = ws + WS_U;
    float* V    = ws + WS_V;
    float* TMP  = ws + WS_TMP;
    float* SC   = ws + WS_SC;
    unsigned* BAR = (unsigned*)(ws + WS_BAR);

    // spectral normalization of W_h
    k_normvec<<<1, 256, 0, stream>>>(u0, U, SC, 0, 0);
    for (int it = 0; it < 3; ++it) {
        k_matvecT<<<256, 256, 0, stream>>>(Wh, U, TMP);
        k_normvec<<<1, 256, 0, stream>>>(TMP, V, SC, 1, 0);
        k_matvecN<<<256, 256, 0, stream>>>(Wh, V, TMP);
        k_normvec<<<1, 256, 0, stream>>>(TMP, U, SC, 1, (it == 2) ? 1 : 0);
    }
    k_scalewh<<<1024, 256, 0, stream>>>(Wh, WHS, SC);

    // pre_x = x @ W_x^T + b
    dim3 gg(16, 128);
    k_pregemm<<<gg, 256, 0, stream>>>(x, Wx, bias, PRE);

    // zero barrier flags (ws is re-poisoned before every timed call)
    k_zero<<<2, 256, 0, stream>>>(BAR);

    // sequential scan, per-group barriers, all 256 blocks co-resident
    {
        size_t dynlds = (size_t)(ROWS_PB * S_WH + 2 * DIMSZ) * sizeof(float); // 140288 B
        hipFuncSetAttribute(reinterpret_cast<const void*>(&k_scan_fused),
                            hipFuncAttributeMaxDynamicSharedMemorySize, (int)dynlds);
        const float* h0p = h0;
        const float* prep = PRE;
        const float* whsp = WHS;
        float* hseqp = HSEQ;
        unsigned* barp = BAR;
        void* args[5] = {(void*)&h0p, (void*)&prep, (void*)&whsp, (void*)&hseqp, (void*)&barp};
        hipLaunchCooperativeKernel(reinterpret_cast<const void*>(&k_scan_fused),
                                   dim3(256), dim3(256), args, (unsigned)dynlds, stream);
    }

    // m banks + output
    k_out<<<128, 128, 0, stream>>>(HSEQ, z, m0, a, out);
}

// Round 5
// 3636.381 us; speedup vs baseline: 5.4061x; 5.3797x over previous
//
#include <hip/hip_runtime.h>
#include <math.h>

#define TSTEPS 512
#define BATCH  16
#define DIMSZ  1024
#define NBANK  4
#define ZD     5120            // (1+NB)*DIM
#define HN     16384           // BATCH*DIMSZ
#define ROWS_PB 32
#define ENC    2.0f            // h stored as h+ENC in hseq (range (1,3); poison/zero < 0.5)

// workspace layout (float offsets)
#define WS_WHS  0u
#define WS_PRE  1048576u
#define WS_HSEQ 9437184u
#define WS_U    17825792u
#define WS_V    17826816u
#define WS_TMP  17827840u
#define WS_SC   17828864u

// ---------------- spectral norm helpers ----------------

__global__ __launch_bounds__(256) void k_normvec(const float* __restrict__ in,
                                                 float* __restrict__ outv,
                                                 float* __restrict__ sc,
                                                 int use_eps, int write_scale) {
    __shared__ float red[256];
    int tid = threadIdx.x;
    float4 v = *(const float4*)(in + tid * 4);
    red[tid] = v.x*v.x + v.y*v.y + v.z*v.z + v.w*v.w;
    __syncthreads();
    for (int off = 128; off > 0; off >>= 1) {
        if (tid < off) red[tid] += red[tid + off];
        __syncthreads();
    }
    float total = red[0];
    float nrm   = sqrtf(total);
    float denom = use_eps ? (nrm + 1e-8f) : nrm;
    float inv   = 1.0f / denom;
    float4 o;
    o.x = v.x * inv; o.y = v.y * inv; o.z = v.z * inv; o.w = v.w * inv;
    *(float4*)(outv + tid * 4) = o;
    if (write_scale && tid == 0) {
        float sigma = total / denom;
        sc[0] = 0.99f / (sigma + 1e-8f);
    }
}

__global__ __launch_bounds__(256) void k_matvecT(const float* __restrict__ W,
                                                 const float* __restrict__ vin,
                                                 float* __restrict__ vout) {
    __shared__ float4 red[256];
    int tid = threadIdx.x;
    int i0  = blockIdx.x * 4;
    float4 acc = make_float4(0.f, 0.f, 0.f, 0.f);
#pragma unroll
    for (int q = 0; q < 4; ++q) {
        int j = tid * 4 + q;
        float u = vin[j];
        float4 w = *(const float4*)(W + (size_t)j * DIMSZ + i0);
        acc.x += u * w.x; acc.y += u * w.y; acc.z += u * w.z; acc.w += u * w.w;
    }
    red[tid] = acc;
    __syncthreads();
    for (int off = 128; off > 0; off >>= 1) {
        if (tid < off) {
            float4 a = red[tid], b = red[tid + off];
            a.x += b.x; a.y += b.y; a.z += b.z; a.w += b.w;
            red[tid] = a;
        }
        __syncthreads();
    }
    if (tid == 0) *(float4*)(vout + i0) = red[0];
}

__global__ __launch_bounds__(256) void k_matvecN(const float* __restrict__ W,
                                                 const float* __restrict__ vin,
                                                 float* __restrict__ vout) {
    __shared__ float red[256];
    int tid = threadIdx.x;
    int i0  = blockIdx.x * 4;
    int ii  = tid >> 6, jg = tid & 63;
    const float* wr = W + (size_t)(i0 + ii) * DIMSZ + jg * 16;
    const float* vv = vin + jg * 16;
    float s = 0.f;
#pragma unroll
    for (int q = 0; q < 4; ++q) {
        float4 w = *(const float4*)(wr + q * 4);
        float4 v = *(const float4*)(vv + q * 4);
        s += w.x*v.x + w.y*v.y + w.z*v.z + w.w*v.w;
    }
    red[tid] = s;
    __syncthreads();
    if (tid < 4) {
        float t2 = 0.f;
        for (int j = 0; j < 64; ++j) t2 += red[tid * 64 + j];
        vout[i0 + tid] = t2;
    }
}

__global__ __launch_bounds__(256) void k_scalewh(const float* __restrict__ W,
                                                 float* __restrict__ Ws,
                                                 const float* __restrict__ sc) {
    float s = sc[0];
    size_t idx = ((size_t)blockIdx.x * 256 + threadIdx.x) * 4;
    float4 v = *(const float4*)(W + idx);
    v.x *= s; v.y *= s; v.z *= s; v.w *= s;
    *(float4*)(Ws + idx) = v;
}

// fill hseq with 0.0f (robust "not yet written" marker independent of ws poison)
__global__ __launch_bounds__(256) void k_fillz(float* __restrict__ p) {
    size_t idx = ((size_t)blockIdx.x * 256 + threadIdx.x) * 4;
    *(float4*)(p + idx) = make_float4(0.f, 0.f, 0.f, 0.f);
}

// ---------------- pre_x = x @ W_x^T + b ----------------
__global__ __launch_bounds__(256) void k_pregemm(const float* __restrict__ A,
                                                 const float* __restrict__ W,
                                                 const float* __restrict__ bias,
                                                 float* __restrict__ outp) {
    __shared__ __align__(16) float As[16][68];
    __shared__ __align__(16) float Bs[16][68];
    int tid = threadIdx.x;
    int bn = blockIdx.x * 64;
    int bm = blockIdx.y * 64;
    int tx = tid & 15, ty = tid >> 4;
    int lrow = tid >> 2;
    int lk   = (tid & 3) * 4;
    const float* Ap = A + (size_t)(bm + lrow) * DIMSZ + lk;
    const float* Wp = W + (size_t)(bn + lrow) * DIMSZ + lk;
    float acc[4][4] = {{0.f}};
    for (int k0 = 0; k0 < DIMSZ; k0 += 16) {
        float4 av = *(const float4*)(Ap + k0);
        float4 wv = *(const float4*)(Wp + k0);
        __syncthreads();
        As[lk+0][lrow] = av.x; As[lk+1][lrow] = av.y; As[lk+2][lrow] = av.z; As[lk+3][lrow] = av.w;
        Bs[lk+0][lrow] = wv.x; Bs[lk+1][lrow] = wv.y; Bs[lk+2][lrow] = wv.z; Bs[lk+3][lrow] = wv.w;
        __syncthreads();
#pragma unroll
        for (int kk = 0; kk < 16; ++kk) {
            float4 a4 = *(const float4*)&As[kk][ty * 4];
            float4 b4 = *(const float4*)&Bs[kk][tx * 4];
            acc[0][0] += a4.x*b4.x; acc[0][1] += a4.x*b4.y; acc[0][2] += a4.x*b4.z; acc[0][3] += a4.x*b4.w;
            acc[1][0] += a4.y*b4.x; acc[1][1] += a4.y*b4.y; acc[1][2] += a4.y*b4.z; acc[1][3] += a4.y*b4.w;
            acc[2][0] += a4.z*b4.x; acc[2][1] += a4.z*b4.y; acc[2][2] += a4.z*b4.z; acc[2][3] += a4.z*b4.w;
            acc[3][0] += a4.w*b4.x; acc[3][1] += a4.w*b4.y; acc[3][2] += a4.w*b4.z; acc[3][3] += a4.w*b4.w;
        }
    }
    float4 bb = *(const float4*)(bias + bn + tx * 4);
#pragma unroll
    for (int i = 0; i < 4; ++i) {
        float4 o;
        o.x = acc[i][0] + bb.x; o.y = acc[i][1] + bb.y;
        o.z = acc[i][2] + bb.z; o.w = acc[i][3] + bb.w;
        *(float4*)(outp + (size_t)(bm + ty * 4 + i) * DIMSZ + bn + tx * 4) = o;
    }
}

// ---------------- sequential h-scan: fence-free data-as-flag exchange -------
// 256 blocks x 256 threads (cooperative: co-residency guarantee, no grid.sync).
// group g = bid&7 owns batches {2g,2g+1}; block s = bid>>3 owns Wh rows
// [32s,32s+32), held in REGISTERS (w[4][8] float4 per thread = 128 VGPR).
// Exchange: h encoded as h+2 in hseq[t]; producers use relaxed agent-scope
// stores (write-through to coherence point), consumers poll relaxed agent-scope
// loads until >0.5. No fences, no flags, no RMW anywhere in the loop.
__global__ __launch_bounds__(256, 1) void k_scan_poll(const float* __restrict__ h0,
                                                      const float* __restrict__ pre,
                                                      const float* __restrict__ whs,
                                                      float* hseq) {
    __shared__ __align__(16) float hs[2 * DIMSZ];
    int tid = threadIdx.x, bid = blockIdx.x;
    int g = bid & 7, s = bid >> 3;
    int b0 = g * 2;
    int j0 = s * ROWS_PB;
    int rg = tid >> 5;   // 0..7: owns rows j0+rg*4 .. +3
    int dg = tid & 31;   // k-split lane: k = dg*4 + i*128

    // Wh slice -> registers (static indexing, fully unrolled)
    float4 w[4][8];
#pragma unroll
    for (int rr = 0; rr < 4; ++rr) {
        const float* wr = whs + (size_t)(j0 + rg * 4 + rr) * DIMSZ + dg * 4;
#pragma unroll
        for (int i = 0; i < 8; ++i)
            w[rr][i] = *(const float4*)(wr + (size_t)i * 128);
    }

    for (int t = 0; t < TSTEPS; ++t) {
        // prefetch pre[t] early (independent of the recurrence)
        float4 pa = make_float4(0.f,0.f,0.f,0.f), pb = pa;
        if (dg == 0) {
            const float* prow = pre + (size_t)t * HN;
            pa = *(const float4*)(prow + (size_t)b0 * DIMSZ + j0 + rg * 4);
            pb = *(const float4*)(prow + (size_t)(b0 + 1) * DIMSZ + j0 + rg * 4);
        }

        // gather h_{t-1} (2048 floats, 8 per thread)
        float v[8];
        if (t == 0) {
            const float* src = h0 + (size_t)b0 * DIMSZ;
#pragma unroll
            for (int q = 0; q < 8; ++q) v[q] = src[q * 256 + tid];
        } else {
            const float* src = hseq + (size_t)(t - 1) * HN + (size_t)b0 * DIMSZ;
#pragma unroll
            for (int q = 0; q < 8; ++q)
                v[q] = __hip_atomic_load(src + q * 256 + tid,
                                         __ATOMIC_RELAXED, __HIP_MEMORY_SCOPE_AGENT);
            unsigned miss = 0xFFu;
            while (miss) {
#pragma unroll
                for (int q = 0; q < 8; ++q) {
                    if (miss & (1u << q)) {
                        if (v[q] > 0.5f) miss &= ~(1u << q);
                        else v[q] = __hip_atomic_load(src + q * 256 + tid,
                                        __ATOMIC_RELAXED, __HIP_MEMORY_SCOPE_AGENT);
                    }
                }
            }
#pragma unroll
            for (int q = 0; q < 8; ++q) v[q] -= ENC;
        }
        __syncthreads();                 // previous step done reading hs
#pragma unroll
        for (int q = 0; q < 8; ++q) hs[q * 256 + tid] = v[q];
        __syncthreads();

        // matvec: acc[rr][batch] over this thread's 32 k values
        float acc[4][2] = {{0.f,0.f},{0.f,0.f},{0.f,0.f},{0.f,0.f}};
#pragma unroll
        for (int i = 0; i < 8; ++i) {
            int k = dg * 4 + i * 128;
            float4 ha = *(const float4*)&hs[k];
            float4 hb = *(const float4*)&hs[DIMSZ + k];
#pragma unroll
            for (int rr = 0; rr < 4; ++rr) {
                float4 ww = w[rr][i];
                acc[rr][0] += ww.x*ha.x + ww.y*ha.y + ww.z*ha.z + ww.w*ha.w;
                acc[rr][1] += ww.x*hb.x + ww.y*hb.y + ww.z*hb.z + ww.w*hb.w;
            }
        }
#pragma unroll
        for (int off = 16; off > 0; off >>= 1)
#pragma unroll
            for (int rr = 0; rr < 4; ++rr) {
                acc[rr][0] += __shfl_down(acc[rr][0], off, 32);
                acc[rr][1] += __shfl_down(acc[rr][1], off, 32);
            }
        if (dg == 0) {
            float* d0 = hseq + (size_t)t * HN + (size_t)b0 * DIMSZ + j0 + rg * 4;
            float* d1 = d0 + DIMSZ;
            float e0 = tanhf(acc[0][0] + pa.x) + ENC;
            float e1 = tanhf(acc[1][0] + pa.y) + ENC;
            float e2 = tanhf(acc[2][0] + pa.z) + ENC;
            float e3 = tanhf(acc[3][0] + pa.w) + ENC;
            __hip_atomic_store(d0 + 0, e0, __ATOMIC_RELAXED, __HIP_MEMORY_SCOPE_AGENT);
            __hip_atomic_store(d0 + 1, e1, __ATOMIC_RELAXED, __HIP_MEMORY_SCOPE_AGENT);
            __hip_atomic_store(d0 + 2, e2, __ATOMIC_RELAXED, __HIP_MEMORY_SCOPE_AGENT);
            __hip_atomic_store(d0 + 3, e3, __ATOMIC_RELAXED, __HIP_MEMORY_SCOPE_AGENT);
            e0 = tanhf(acc[0][1] + pb.x) + ENC;
            e1 = tanhf(acc[1][1] + pb.y) + ENC;
            e2 = tanhf(acc[2][1] + pb.z) + ENC;
            e3 = tanhf(acc[3][1] + pb.w) + ENC;
            __hip_atomic_store(d1 + 0, e0, __ATOMIC_RELAXED, __HIP_MEMORY_SCOPE_AGENT);
            __hip_atomic_store(d1 + 1, e1, __ATOMIC_RELAXED, __HIP_MEMORY_SCOPE_AGENT);
            __hip_atomic_store(d1 + 2, e2, __ATOMIC_RELAXED, __HIP_MEMORY_SCOPE_AGENT);
            __hip_atomic_store(d1 + 3, e3, __ATOMIC_RELAXED, __HIP_MEMORY_SCOPE_AGENT);
        }
    }
}

// ---------------- m-banks + output (decodes h = enc - 2) ----------------
__global__ __launch_bounds__(128) void k_out(const float* __restrict__ hseq,
                                             const float* __restrict__ z,
                                             const float* __restrict__ m0,
                                             const float* __restrict__ a,
                                             float* __restrict__ out) {
    int gt = blockIdx.x * 128 + threadIdx.x;   // 0..16383
    int b = gt >> 10, d = gt & 1023;
    float al[NBANK], om[NBANK], m[NBANK];
#pragma unroll
    for (int k = 0; k < NBANK; ++k) {
        float av = a[k * DIMSZ + d];
        al[k] = 1.0f / (1.0f + expf(-av));
        om[k] = 1.0f - al[k];
        m[k]  = m0[(size_t)k * HN + b * DIMSZ + d];
    }
    const float* zb = z + (size_t)b * ZD + d;
    const float* hb = hseq + (size_t)b * DIMSZ + d;
    float* ob = out + (size_t)b * DIMSZ + d;
    float h = 0.f;
    for (int t = 0; t < TSTEPS; ++t) {
        h = hb[(size_t)t * HN] - ENC;          // decode
        const float* zt = zb + (size_t)t * (BATCH * ZD);
        float z0 = zt[0];
        float o = h * (z0 / (1.0f + expf(-z0)));
#pragma unroll
        for (int k = 0; k < NBANK; ++k) {
            m[k] = al[k] * m[k] + om[k] * h;
            float zk = zt[(k + 1) * DIMSZ];
            o += m[k] * (zk / (1.0f + expf(-zk)));
        }
        ob[(size_t)t * HN] = o;
    }
    out[(size_t)TSTEPS * HN + b * DIMSZ + d] = h;
#pragma unroll
    for (int k = 0; k < NBANK; ++k)
        out[(size_t)TSTEPS * HN + HN + (size_t)k * HN + b * DIMSZ + d] = m[k];
}

// ---------------- launch ----------------
extern "C" void kernel_launch(void* const* d_in, const int* in_sizes, int n_in,
                              void* d_out, int out_size, void* d_ws, size_t ws_size,
                              hipStream_t stream) {
    const float* x    = (const float*)d_in[0];
    const float* z    = (const float*)d_in[1];
    const float* h0   = (const float*)d_in[2];
    const float* m0   = (const float*)d_in[3];
    const float* Wx   = (const float*)d_in[4];
    const float* Wh   = (const float*)d_in[5];
    const float* bias = (const float*)d_in[6];
    const float* a    = (const float*)d_in[7];
    const float* u0   = (const float*)d_in[8];
    float* out = (float*)d_out;
    float* ws  = (float*)d_ws;

    float* WHS  = ws + WS_WHS;
    float* PRE  = ws + WS_PRE;
    float* HSEQ = ws + WS_HSEQ;
    float* U    = ws + WS_U;
    float* V    = ws + WS_V;
    float* TMP  = ws + WS_TMP;
    float* SC   = ws + WS_SC;

    // spectral normalization of W_h
    k_normvec<<<1, 256, 0, stream>>>(u0, U, SC, 0, 0);
    for (int it = 0; it < 3; ++it) {
        k_matvecT<<<256, 256, 0, stream>>>(Wh, U, TMP);
        k_normvec<<<1, 256, 0, stream>>>(TMP, V, SC, 1, 0);
        k_matvecN<<<256, 256, 0, stream>>>(Wh, V, TMP);
        k_normvec<<<1, 256, 0, stream>>>(TMP, U, SC, 1, (it == 2) ? 1 : 0);
    }
    k_scalewh<<<1024, 256, 0, stream>>>(Wh, WHS, SC);

    // clear hseq to 0.0 ("not written"); kernel-end release flushes L2s
    k_fillz<<<8192, 256, 0, stream>>>(HSEQ);

    // pre_x = x @ W_x^T + b
    dim3 gg(16, 128);
    k_pregemm<<<gg, 256, 0, stream>>>(x, Wx, bias, PRE);

    // scan: cooperative (co-residency only; no grid sync inside)
    {
        const float* h0p = h0;
        const float* prep = PRE;
        const float* whsp = WHS;
        float* hseqp = HSEQ;
        void* args[4] = {(void*)&h0p, (void*)&prep, (void*)&whsp, (void*)&hseqp};
        hipLaunchCooperativeKernel(reinterpret_cast<const void*>(&k_scan_poll),
                                   dim3(256), dim3(256), args, 0, stream);
    }

    // m banks + output
    k_out<<<128, 128, 0, stream>>>(HSEQ, z, m0, a, out);
}